// Round 13
// baseline (145.671 us; speedup 1.0000x reference)
//
#include <hip/hip_runtime.h>
#include <hip/hip_fp16.h>
#include <cstdint>

typedef _Float16 half8_t __attribute__((ext_vector_type(8)));
typedef float f32x4 __attribute__((ext_vector_type(4)));

#define D_ 1024
#define B_ 4
#define N_ 2048
#define M_ (B_*N_)   // 8192 rows
#define NC_ 3072     // fused q|k|v output cols

// ---------------- workspace layout (bytes, all 256-aligned) ----------------
#define OFF_WCAT  0u            // 3072*1024*2  = 6291456
#define OFF_BCAT  6291456u      // 3072*4       = 12288
#define OFF_XB    6303744u      // 8192*1024*2  = 16777216
#define OFF_Q     23080960u
#define OFF_K     39858176u
#define OFF_V     56635392u
#define OFF_ZP    73412608u     // 8192*32*4    = 1048576
#define OFF_DEXP  74461184u     // 8192*4
#define OFF_SV    74493952u     // 4*64*1024*4 = 1048576 (32-row chunk sums, f32)
#define OFF_QC    75542528u     // 256B atomic work-queue counter (memset/call)

// ---------------- async global->LDS, 16B per lane ----------------
__device__ __forceinline__ void gload_lds16(const void* g, void* l) {
  __builtin_amdgcn_global_load_lds(
      (const __attribute__((address_space(1))) unsigned int*)(uintptr_t)g,
      (__attribute__((address_space(3))) unsigned int*)(uintptr_t)l, 16, 0, 0);
}

// ============================================================================
// 256^2 8-phase core (round-2/4 proven)
// ============================================================================
__device__ __forceinline__ void calc_soff(int tid, int soff[4]) {
#pragma unroll
  for (int i = 0; i < 4; ++i) {
    int L = i * 8192 + tid * 16;
    int s = L >> 10;
    int w = L & 1023;
    w ^= ((w >> 9) & 1) << 5;
    int r  = (s >> 1) * 16 + (w >> 6);
    int kb = (s & 1) * 64 + (w & 63);
    soff[i] = r * 2048 + kb;
  }
}

#define MFMA_QUAD(QM, QN)                                                     \
  _Pragma("unroll")                                                           \
  for (int ks = 0; ks < 2; ++ks)                                              \
    _Pragma("unroll")                                                         \
    for (int mf = 0; mf < 4; ++mf)                                            \
      _Pragma("unroll")                                                       \
      for (int nf = 0; nf < 2; ++nf)                                          \
        acc[(QM)*4 + mf][(QN)*2 + nf] = __builtin_amdgcn_mfma_f32_16x16x32_f16( \
            a[mf][ks], b[(QN)][nf][ks], acc[(QM)*4 + mf][(QN)*2 + nf], 0, 0, 0);

__device__ __forceinline__ void gemm256_8ph(const char* Ag, const char* Bg,
                                            char* smem, f32x4 acc[8][4]) {
  const int tid  = threadIdx.x;
  const int lane = tid & 63;
  const int wave = tid >> 6;
  const int wm = wave >> 2, wn = wave & 3;

  int soff[4];
  calc_soff(tid, soff);
  const int wlane = (((lane & 15) * 64 + (lane >> 4) * 16)) ^ (((lane >> 3) & 1) << 5);

#pragma unroll
  for (int i = 0; i < 4; ++i) gload_lds16(Ag + soff[i], smem + i * 8192 + tid * 16);
#pragma unroll
  for (int i = 0; i < 4; ++i) gload_lds16(Bg + soff[i], smem + 32768 + i * 8192 + tid * 16);
  asm volatile("s_waitcnt vmcnt(0)" ::: "memory");
  __builtin_amdgcn_s_barrier();

  for (int t = 0; t < 16; ++t) {
    char* A0  = smem + ((t & 1) << 16);
    char* B0  = A0 + 32768;
    char* A1  = smem + (((t + 1) & 1) << 16);
    char* B1s = A1 + 32768;
    const half8_t* ap = (const half8_t*)(A0 + wm * 16384 + wlane);
    const half8_t* bp = (const half8_t*)(B0 + wn * 8192 + wlane);
    const char* Agn = Ag + (t + 1) * 128;
    const char* Bgn = Bg + (t + 1) * 128;
    const bool pre = (t < 15);

    half8_t a[4][2];
    half8_t b[2][2][2];

#pragma unroll
    for (int mf = 0; mf < 4; ++mf)
#pragma unroll
      for (int ks = 0; ks < 2; ++ks)
        a[mf][ks] = ap[(mf * 2 + ks) * 64];
#pragma unroll
    for (int nf = 0; nf < 2; ++nf)
#pragma unroll
      for (int ks = 0; ks < 2; ++ks)
        b[0][nf][ks] = bp[(nf * 2 + ks) * 64];
    if (pre) {
#pragma unroll
      for (int i = 0; i < 4; ++i) gload_lds16(Agn + soff[i], A1 + i * 8192 + tid * 16);
    }
    __builtin_amdgcn_s_barrier();
    asm volatile("s_waitcnt lgkmcnt(0)" ::: "memory");
    __builtin_amdgcn_s_setprio(1);
    MFMA_QUAD(0, 0)
    __builtin_amdgcn_s_setprio(0);
    __builtin_amdgcn_s_barrier();

#pragma unroll
    for (int nf = 0; nf < 2; ++nf)
#pragma unroll
      for (int ks = 0; ks < 2; ++ks)
        b[1][nf][ks] = bp[((2 + nf) * 2 + ks) * 64];
    if (pre) {
#pragma unroll
      for (int i = 0; i < 4; ++i) gload_lds16(Bgn + soff[i], B1s + i * 8192 + tid * 16);
    }
    __builtin_amdgcn_s_barrier();
    asm volatile("s_waitcnt lgkmcnt(0)" ::: "memory");
    __builtin_amdgcn_s_setprio(1);
    MFMA_QUAD(0, 1)
    __builtin_amdgcn_s_setprio(0);
    __builtin_amdgcn_s_barrier();

#pragma unroll
    for (int mf = 0; mf < 4; ++mf)
#pragma unroll
      for (int ks = 0; ks < 2; ++ks)
        a[mf][ks] = ap[((4 + mf) * 2 + ks) * 64];
    __builtin_amdgcn_s_barrier();
    asm volatile("s_waitcnt lgkmcnt(0)" ::: "memory");
    __builtin_amdgcn_s_setprio(1);
    MFMA_QUAD(1, 0)
    __builtin_amdgcn_s_setprio(0);
    __builtin_amdgcn_s_barrier();

    __builtin_amdgcn_s_setprio(1);
    MFMA_QUAD(1, 1)
    __builtin_amdgcn_s_setprio(0);
    if (pre) asm volatile("s_waitcnt vmcnt(0)" ::: "memory");
    __builtin_amdgcn_s_barrier();
  }
}

// ---------------- K1: fp32->fp16 convert ----------------
__global__ __launch_bounds__(256) void k_prep(
    const float* __restrict__ x, const float* __restrict__ wq, const float* __restrict__ wk,
    const float* __restrict__ wv, const float* __restrict__ bq, const float* __restrict__ bk,
    const float* __restrict__ bv, __half* __restrict__ xb, __half* __restrict__ wcat,
    float* __restrict__ bcat) {
  const int NX4 = (M_ * D_) / 4;
  const int NW4 = (D_ * D_) / 4;
  const int TOT = NX4 + 3 * NW4;
  int tid0 = blockIdx.x * 256 + threadIdx.x;
  int stride = gridDim.x * 256;
  for (int i = tid0; i < TOT; i += stride) {
    float4 f; __half* dst;
    if (i < NX4) {
      f = ((const float4*)x)[i];
      dst = xb + 4 * (size_t)i;
    } else {
      int j = i - NX4; int w = j / NW4; int o = j - w * NW4;
      const float* src = (w == 0) ? wq : (w == 1) ? wk : wv;
      f = ((const float4*)src)[o];
      dst = wcat + (size_t)w * (D_ * D_) + 4 * (size_t)o;
    }
    __half h0 = __float2half(f.x), h1 = __float2half(f.y),
           h2 = __float2half(f.z), h3 = __float2half(f.w);
    ushort4 u = { __half_as_ushort(h0), __half_as_ushort(h1),
                  __half_as_ushort(h2), __half_as_ushort(h3) };
    *((ushort4*)dst) = u;
  }
  if (tid0 < NC_)
    bcat[tid0] = (tid0 < 1024) ? bq[tid0] : (tid0 < 2048) ? bk[tid0 - 1024] : bv[tid0 - 2048];
}

// ---------------- K2: q,k GEMM at 256^2, grid 256 = 1 exact round ----------
__global__ __launch_bounds__(512, 2) void k_qk(
    const __half* __restrict__ xb, const __half* __restrict__ wcat,
    const float* __restrict__ bcat,
    __half* __restrict__ q, __half* __restrict__ kx) {
  __shared__ __align__(16) char smem[131072];
  int bid = blockIdx.x;
  int tile = (bid & 7) * 32 + (bid >> 3);       // XCD-chunked, 256 = 8*32
  int bm = tile >> 3, bn = tile & 7;            // 32 x 8 (cols 0..2047)

  f32x4 acc[8][4];
#pragma unroll
  for (int i = 0; i < 8; ++i)
#pragma unroll
    for (int j = 0; j < 4; ++j) acc[i][j] = f32x4{0.f, 0.f, 0.f, 0.f};

  gemm256_8ph((const char*)(xb + (size_t)bm * 256 * D_),
              (const char*)(wcat + (size_t)bn * 256 * D_), smem, acc);

  const int lane = threadIdx.x & 63;
  const int wave = threadIdx.x >> 6;
  const int wm = wave >> 2, wn = wave & 3;
  __half* outp = (bn < 4) ? q : kx;
  int colbase = (bn & 3) * 256 + wn * 64;
#pragma unroll
  for (int nf = 0; nf < 4; ++nf) {
    int col = colbase + nf * 16 + (lane & 15);
    float bias = bcat[bn * 256 + wn * 64 + nf * 16 + (lane & 15)];
#pragma unroll
    for (int mf = 0; mf < 8; ++mf) {
#pragma unroll
      for (int rr = 0; rr < 4; ++rr) {
        int m = bm * 256 + wm * 128 + mf * 16 + (lane >> 4) * 4 + rr;
        outp[(size_t)m * D_ + col] = __float2half(acc[mf][nf][rr] + bias);
      }
    }
  }
}

// ============================================================================
// K3: stats tiles (fixed, tile<144) + v-GEMM 256^2 tiles (atomic queue, 128)
// with fused Sv epilogue. Grid 256 = 1 round; queue auto-balances.
// ============================================================================
__global__ __launch_bounds__(512, 2) void k_statsv(
    const __half* __restrict__ q, const __half* __restrict__ kx,
    const __half* __restrict__ xb, const __half* __restrict__ wcat,
    const float* __restrict__ bcat,
    __half* __restrict__ v, float* __restrict__ Sv,
    float* __restrict__ Zpart, float* __restrict__ dexp, int* __restrict__ qc) {
  __shared__ __align__(16) char smem[131072];
  __shared__ int s_vt;
  const int thr  = threadIdx.x;
  const int lane = thr & 63;
  const int wave = thr >> 6;
  const int wm = wave >> 2, wn = wave & 3;

  int bid = blockIdx.x;
  int tile = (bid & 7) * 32 + (bid >> 3);       // 256 = 8*32

  if (tile < 144) {
    // ---- stats tile (unchanged math) ----
    int b = tile / 36;
    int r = tile % 36;
    int ti = 0;
    while (r >= 8 - ti) { r -= 8 - ti; ++ti; }
    int tj = ti + r;

    f32x4 acc[8][4];
#pragma unroll
    for (int i = 0; i < 8; ++i)
#pragma unroll
      for (int j = 0; j < 4; ++j) acc[i][j] = f32x4{0.f, 0.f, 0.f, 0.f};

    const size_t base = (size_t)b * N_ * D_;
    gemm256_8ph((const char*)(q + base + (size_t)ti * 256 * D_),
                (const char*)(kx + base + (size_t)tj * 256 * D_), smem, acc);

    const bool offd = (tj > ti);
    const float scale = 0.03125f;               // 1/sqrt(1024)
    int zr0 = b * N_ + ti * 256;
#pragma unroll
    for (int mf = 0; mf < 8; ++mf) {
#pragma unroll
      for (int rr = 0; rr < 4; ++rr) {
        int il = wm * 128 + mf * 16 + (lane >> 4) * 4 + rr;
        float ssum = 0.f;
#pragma unroll
        for (int nf = 0; nf < 4; ++nf) {
          int jl = wn * 64 + nf * 16 + (lane & 15);
          float e = __expf(acc[mf][nf][rr] * scale);
          bool keep = offd || (jl >= il);
          if (!offd && jl == il) dexp[zr0 + il] = e;
          ssum += keep ? e : 0.f;
        }
        ssum += __shfl_xor(ssum, 1);
        ssum += __shfl_xor(ssum, 2);
        ssum += __shfl_xor(ssum, 4);
        ssum += __shfl_xor(ssum, 8);
        if ((lane & 15) == 0)
          Zpart[(size_t)(zr0 + il) * 32 + tj * 4 + wn] = ssum;
      }
    }
  }

  // ---- v-GEMM work queue: 128 tiles of 256x256 (32 bm x 4 bn) ----
  for (;;) {
    __syncthreads();
    if (thr == 0) s_vt = atomicAdd(qc, 1);
    __syncthreads();
    int vt = s_vt;
    if (vt >= 128) break;
    int bm = vt >> 2, bn = vt & 3;

    f32x4 acc[8][4];
#pragma unroll
    for (int i = 0; i < 8; ++i)
#pragma unroll
      for (int j = 0; j < 4; ++j) acc[i][j] = f32x4{0.f, 0.f, 0.f, 0.f};

    gemm256_8ph((const char*)(xb + (size_t)bm * 256 * D_),
                (const char*)(wcat + (size_t)(2048 + bn * 256) * D_), smem, acc);

#pragma unroll
    for (int nf = 0; nf < 4; ++nf) {
      int col = bn * 256 + wn * 64 + nf * 16 + (lane & 15);
      float bias = bcat[2048 + col];
#pragma unroll
      for (int mf = 0; mf < 8; ++mf) {
#pragma unroll
        for (int rr = 0; rr < 4; ++rr) {
          int m = bm * 256 + wm * 128 + mf * 16 + (lane >> 4) * 4 + rr;
          v[(size_t)m * D_ + col] = __float2half(acc[mf][nf][rr] + bias);
        }
      }
      // Sv: 32-row chunk sums (chunk = mf pair), reduce across lane>>4 groups
#pragma unroll
      for (int t = 0; t < 4; ++t) {
        float s = 8.f * bias;
#pragma unroll
        for (int dd = 0; dd < 2; ++dd)
#pragma unroll
          for (int rr = 0; rr < 4; ++rr)
            s += acc[t * 2 + dd][nf][rr];
        s += __shfl_xor(s, 16);
        s += __shfl_xor(s, 32);
        if ((lane >> 4) == 0)
          Sv[(size_t)(bm * 8 + wm * 4 + t) * D_ + col] = s;
      }
    }
  }
}

// ---------------- K4: denom + prefix-scan blend -> output (vec4) ----------
__global__ __launch_bounds__(256) void k_out(
    const __half* __restrict__ v, const float* __restrict__ Sv,
    const float* __restrict__ Zpart, const float* __restrict__ dexp,
    float* __restrict__ out) {
  __shared__ float sInv[32], sCd[32];
  int slab = blockIdx.x;
  int b = slab >> 6, c = slab & 63;
  int dg = threadIdx.x;
  int d0 = dg * 4;
  int zi0 = b * N_ + c * 32;

  if (dg < 32) {
    int i  = c * 32 + dg;
    int row = zi0 + dg;
    int t0 = (i >> 8) * 4;
    float z = 0.f;
    for (int t = t0; t < 32; ++t) z += Zpart[(size_t)row * 32 + t];
    float iv = 1.f / ((float)i + z);
    sInv[dg] = iv;
    sCd[dg]  = dexp[row] * iv;
  }
  __syncthreads();

  f32x4 run = {0.f, 0.f, 0.f, 0.f};
  for (int cc = 0; cc < c; ++cc) {
    f32x4 sv = *(const f32x4*)(Sv + (size_t)((b << 6) + cc) * D_ + d0);
    run[0] += sv[0]; run[1] += sv[1]; run[2] += sv[2]; run[3] += sv[3];
  }
  const ushort4* vp = (const ushort4*)(v + (size_t)zi0 * D_ + d0);
  float* op = out + (size_t)zi0 * D_ + d0;
#pragma unroll 4
  for (int r2 = 0; r2 < 32; ++r2) {
    ushort4 u = vp[r2 * (D_ / 4)];
    f32x4 vi;
    vi[0] = __half2float(__ushort_as_half(u.x));
    vi[1] = __half2float(__ushort_as_half(u.y));
    vi[2] = __half2float(__ushort_as_half(u.z));
    vi[3] = __half2float(__ushort_as_half(u.w));
    float iv = sInv[r2], cd = sCd[r2];
    f32x4 o;
    o[0] = run[0] * iv + cd * vi[0];
    o[1] = run[1] * iv + cd * vi[1];
    o[2] = run[2] * iv + cd * vi[2];
    o[3] = run[3] * iv + cd * vi[3];
    *(f32x4*)(op + (size_t)r2 * D_) = o;
    run[0] += vi[0]; run[1] += vi[1]; run[2] += vi[2]; run[3] += vi[3];
  }
}

extern "C" void kernel_launch(void* const* d_in, const int* in_sizes, int n_in,
                              void* d_out, int out_size, void* d_ws, size_t ws_size,
                              hipStream_t stream) {
  const float* x  = (const float*)d_in[0];
  const float* wq = (const float*)d_in[1];
  const float* bq = (const float*)d_in[2];
  const float* wk = (const float*)d_in[3];
  const float* bk = (const float*)d_in[4];
  const float* wv = (const float*)d_in[5];
  const float* bv = (const float*)d_in[6];
  float* out = (float*)d_out;
  char* ws = (char*)d_ws;

  __half* wcat = (__half*)(ws + OFF_WCAT);
  float*  bcat = (float*)(ws + OFF_BCAT);
  __half* xb   = (__half*)(ws + OFF_XB);
  __half* q    = (__half*)(ws + OFF_Q);
  __half* k    = (__half*)(ws + OFF_K);
  __half* v    = (__half*)(ws + OFF_V);
  float* Zpart = (float*)(ws + OFF_ZP);
  float* dexp  = (float*)(ws + OFF_DEXP);
  float* Sv    = (float*)(ws + OFF_SV);
  int*   qc    = (int*)(ws + OFF_QC);

  hipMemsetAsync((void*)qc, 0, 256, stream);
  k_prep<<<dim3(2048), dim3(256), 0, stream>>>(x, wq, wk, wv, bq, bk, bv, xb, wcat, bcat);
  k_qk<<<dim3(256), dim3(512), 0, stream>>>(xb, wcat, bcat, q, k);
  k_statsv<<<dim3(256), dim3(512), 0, stream>>>(q, k, xb, wcat, bcat, v, Sv, Zpart, dexp, qc);
  k_out<<<dim3(256), dim3(256), 0, stream>>>(v, Sv, Zpart, dexp, out);
}

// Round 14
// 127.790 us; speedup vs baseline: 1.1399x; 1.1399x over previous
//
#include <hip/hip_runtime.h>
#include <hip/hip_fp16.h>
#include <cstdint>

typedef _Float16 half8_t __attribute__((ext_vector_type(8)));
typedef float f32x4 __attribute__((ext_vector_type(4)));

#define D_ 1024
#define B_ 4
#define N_ 2048
#define M_ (B_*N_)   // 8192 rows
#define NC_ 3072     // fused q|k|v output cols

// ---------------- workspace layout (bytes, all 256-aligned) ----------------
#define OFF_WCAT  0u            // 3072*1024*2  = 6291456
#define OFF_BCAT  6291456u      // 3072*4       = 12288
#define OFF_XB    6303744u      // 8192*1024*2  = 16777216
#define OFF_Q     23080960u
#define OFF_K     39858176u
#define OFF_V     56635392u
#define OFF_ZP    73412608u     // 8192*32*4    = 1048576
#define OFF_DEXP  74461184u     // 8192*4
#define OFF_SV    74493952u     // 4*64*1024*4 = 1048576 (32-row chunk sums, f32)

// ---------------- async global->LDS, 16B per lane ----------------
__device__ __forceinline__ void gload_lds16(const void* g, void* l) {
  __builtin_amdgcn_global_load_lds(
      (const __attribute__((address_space(1))) unsigned int*)(uintptr_t)g,
      (__attribute__((address_space(3))) unsigned int*)(uintptr_t)l, 16, 0, 0);
}

// ============================================================================
// 128^2 m97-structure core (proven 59.2us for qkv; fine-granularity packing)
// ============================================================================
__device__ __forceinline__ void stage128x64(const __half* rowbase, char* lds, int tid) {
#pragma unroll
  for (int inst = 0; inst < 4; ++inst) {
    int L  = inst * 4096 + tid * 16;
    int r  = L >> 7;
    int cb = L & 127;
    int cbs = cb ^ ((r & 7) << 4);
    gload_lds16((const char*)rowbase + (size_t)r * (D_ * 2) + cbs, lds + L);
  }
}

__device__ __forceinline__ half8_t ldsfrag(const char* lds, int row, int cbyte) {
  int b = (row << 7) + (cbyte ^ ((row & 7) << 4));
  return *reinterpret_cast<const half8_t*>(lds + b);
}

__device__ __forceinline__ void gemm128_core(const __half* Arow0, const __half* Brow0,
                                             char* As, char* Bs, f32x4 acc[4][4]) {
  const int tid  = threadIdx.x;
  const int lane = tid & 63;
  const int wave = tid >> 6;
  const int wm = wave >> 1, wn = wave & 1;
  for (int kt = 0; kt < 16; ++kt) {
    if (kt) __syncthreads();
    stage128x64(Arow0 + kt * 64, As, tid);
    stage128x64(Brow0 + kt * 64, Bs, tid);
    asm volatile("s_waitcnt vmcnt(0)" ::: "memory");
    __syncthreads();
#pragma unroll
    for (int kk = 0; kk < 2; ++kk) {
      const int cbyte = kk * 64 + (lane >> 4) * 16;
      half8_t a[4], b[4];
#pragma unroll
      for (int mf = 0; mf < 4; ++mf) a[mf] = ldsfrag(As, wm * 64 + mf * 16 + (lane & 15), cbyte);
#pragma unroll
      for (int nf = 0; nf < 4; ++nf) b[nf] = ldsfrag(Bs, wn * 64 + nf * 16 + (lane & 15), cbyte);
#pragma unroll
      for (int mf = 0; mf < 4; ++mf)
#pragma unroll
        for (int nf = 0; nf < 4; ++nf)
          acc[mf][nf] = __builtin_amdgcn_mfma_f32_16x16x32_f16(a[mf], b[nf], acc[mf][nf], 0, 0, 0);
    }
  }
}

// ---------------- K1: fp32->fp16 convert ----------------
__global__ __launch_bounds__(256) void k_prep(
    const float* __restrict__ x, const float* __restrict__ wq, const float* __restrict__ wk,
    const float* __restrict__ wv, const float* __restrict__ bq, const float* __restrict__ bk,
    const float* __restrict__ bv, __half* __restrict__ xb, __half* __restrict__ wcat,
    float* __restrict__ bcat) {
  const int NX4 = (M_ * D_) / 4;
  const int NW4 = (D_ * D_) / 4;
  const int TOT = NX4 + 3 * NW4;
  int tid0 = blockIdx.x * 256 + threadIdx.x;
  int stride = gridDim.x * 256;
  for (int i = tid0; i < TOT; i += stride) {
    float4 f; __half* dst;
    if (i < NX4) {
      f = ((const float4*)x)[i];
      dst = xb + 4 * (size_t)i;
    } else {
      int j = i - NX4; int w = j / NW4; int o = j - w * NW4;
      const float* src = (w == 0) ? wq : (w == 1) ? wk : wv;
      f = ((const float4*)src)[o];
      dst = wcat + (size_t)w * (D_ * D_) + 4 * (size_t)o;
    }
    __half h0 = __float2half(f.x), h1 = __float2half(f.y),
           h2 = __float2half(f.z), h3 = __float2half(f.w);
    ushort4 u = { __half_as_ushort(h0), __half_as_ushort(h1),
                  __half_as_ushort(h2), __half_as_ushort(h3) };
    *((ushort4*)dst) = u;
  }
  if (tid0 < NC_)
    bcat[tid0] = (tid0 < 1024) ? bq[tid0] : (tid0 < 2048) ? bk[tid0 - 1024] : bv[tid0 - 2048];
}

// ---------------- K2: fused QKV GEMM (128^2) + XCD bm-chunked swizzle ------
__global__ __launch_bounds__(256) void k_qkv(
    const __half* __restrict__ xb, const __half* __restrict__ wcat,
    const float* __restrict__ bcat,
    __half* __restrict__ q, __half* __restrict__ kx, __half* __restrict__ v) {
  __shared__ __align__(16) char smem[32768];
  char* As = smem; char* Bs = smem + 16384;
  int bid = blockIdx.x;
  int wgid = (bid & 7) * 192 + (bid >> 3);   // bijective: 1536 = 8*192
  int bm = wgid / 24, bn = wgid % 24;
  f32x4 acc[4][4];
#pragma unroll
  for (int i = 0; i < 4; ++i)
#pragma unroll
    for (int j = 0; j < 4; ++j) acc[i][j] = f32x4{0.f, 0.f, 0.f, 0.f};
  gemm128_core(xb + (size_t)bm * 128 * D_, wcat + (size_t)bn * 128 * D_, As, Bs, acc);

  const int lane = threadIdx.x & 63;
  const int wave = threadIdx.x >> 6;
  const int wm = wave >> 1, wn = wave & 1;
  int sel = bn >> 3;
  __half* outp = (sel == 0) ? q : (sel == 1) ? kx : v;
#pragma unroll
  for (int nf = 0; nf < 4; ++nf) {
    int nloc = wn * 64 + nf * 16 + (lane & 15);
    float bias = bcat[bn * 128 + nloc];
    int ncol = (bn & 7) * 128 + nloc;
#pragma unroll
    for (int mf = 0; mf < 4; ++mf) {
#pragma unroll
      for (int r = 0; r < 4; ++r) {
        int m = bm * 128 + wm * 64 + mf * 16 + (lane >> 4) * 4 + r;
        outp[(size_t)m * D_ + ncol] = __float2half(acc[mf][nf][r] + bias);
      }
    }
  }
}

// ============================================================================
// K3: 544 stats tiles (128^2, fine granularity) + 128 Sv blocks x 2 slabs.
// Grid 672 = 8*84, XCD-chunked. Stats tiles co-resident 2-3/CU -> good pack.
// ============================================================================
__global__ __launch_bounds__(256) void k_statsv(
    const __half* __restrict__ q, const __half* __restrict__ kx,
    const __half* __restrict__ v,
    float* __restrict__ Zpart, float* __restrict__ dexp, float* __restrict__ Sv) {
  __shared__ __align__(16) char smem[32768];
  int bid = blockIdx.x;
  int tile = (bid & 7) * 84 + (bid >> 3);       // 672 = 8*84

  if (tile >= 544) {
    // ---- Sv path: 2 slabs of 32-row chunk column sums per block ----
    int sid = tile - 544;                 // 0..127
    int dg = threadIdx.x;
    int d0 = dg * 4;
#pragma unroll
    for (int it = 0; it < 2; ++it) {
      int slab = sid * 2 + it;            // 0..255
      int b = slab >> 6, c = slab & 63;
      const ushort4* vp = (const ushort4*)(v + ((size_t)(b * N_ + c * 32)) * D_ + d0);
      f32x4 s = {0.f, 0.f, 0.f, 0.f};
#pragma unroll 8
      for (int r2 = 0; r2 < 32; ++r2) {
        ushort4 u = vp[r2 * (D_ / 4)];
        s[0] += __half2float(__ushort_as_half(u.x));
        s[1] += __half2float(__ushort_as_half(u.y));
        s[2] += __half2float(__ushort_as_half(u.z));
        s[3] += __half2float(__ushort_as_half(u.w));
      }
      *(f32x4*)(Sv + (size_t)slab * D_ + d0) = s;
    }
    return;
  }

  // ---- stats tile (r1-proven 128^2 math) ----
  int b = tile / 136;
  int r = tile % 136;
  int ti = 0;
  while (r >= 16 - ti) { r -= 16 - ti; ++ti; }
  int tj = ti + r;

  f32x4 acc[4][4];
#pragma unroll
  for (int i = 0; i < 4; ++i)
#pragma unroll
    for (int j = 0; j < 4; ++j) acc[i][j] = f32x4{0.f, 0.f, 0.f, 0.f};
  const size_t base = (size_t)b * N_ * D_;
  gemm128_core(q + base + (size_t)ti * 128 * D_, kx + base + (size_t)tj * 128 * D_,
               smem, smem + 16384, acc);

  const int lane = threadIdx.x & 63;
  const int wave = threadIdx.x >> 6;
  const int wm = wave >> 1, wn = wave & 1;
  const bool offd = (tj > ti);
  const float scale = 0.03125f;            // 1/sqrt(1024)
  int zrow0 = b * N_ + ti * 128;
#pragma unroll
  for (int mf = 0; mf < 4; ++mf) {
#pragma unroll
    for (int rg = 0; rg < 4; ++rg) {
      int il = wm * 64 + mf * 16 + (lane >> 4) * 4 + rg;
      float ssum = 0.f;
#pragma unroll
      for (int nf = 0; nf < 4; ++nf) {
        int jl = wn * 64 + nf * 16 + (lane & 15);
        float e = __expf(acc[mf][nf][rg] * scale);
        bool keep = offd || (jl >= il);
        if (!offd && jl == il) dexp[zrow0 + il] = e;
        ssum += keep ? e : 0.f;
      }
      ssum += __shfl_xor(ssum, 1);
      ssum += __shfl_xor(ssum, 2);
      ssum += __shfl_xor(ssum, 4);
      ssum += __shfl_xor(ssum, 8);
      if ((lane & 15) == 0)
        Zpart[(size_t)(zrow0 + il) * 32 + tj * 2 + wn] = ssum;
    }
  }
}

// ---------------- K4: denom + prefix-scan blend -> output (vec4) ----------
__global__ __launch_bounds__(256) void k_out(
    const __half* __restrict__ v, const float* __restrict__ Sv,
    const float* __restrict__ Zpart, const float* __restrict__ dexp,
    float* __restrict__ out) {
  __shared__ float sInv[32], sCd[32];
  int slab = blockIdx.x;
  int b = slab >> 6, c = slab & 63;
  int dg = threadIdx.x;
  int d0 = dg * 4;
  int zi0 = b * N_ + c * 32;

  if (dg < 32) {
    int i  = c * 32 + dg;                 // row within batch
    int row = zi0 + dg;
    int t0 = (i >> 7) * 2;                // first valid Zpart slot (128-tiles)
    float z = 0.f;
    for (int t = t0; t < 32; ++t) z += Zpart[(size_t)row * 32 + t];
    float iv = 1.f / ((float)i + z);
    sInv[dg] = iv;
    sCd[dg]  = dexp[row] * iv;
  }
  __syncthreads();

  f32x4 run = {0.f, 0.f, 0.f, 0.f};
  for (int cc = 0; cc < c; ++cc) {
    f32x4 sv = *(const f32x4*)(Sv + (size_t)((b << 6) + cc) * D_ + d0);
    run[0] += sv[0]; run[1] += sv[1]; run[2] += sv[2]; run[3] += sv[3];
  }
  const ushort4* vp = (const ushort4*)(v + (size_t)zi0 * D_ + d0);
  float* op = out + (size_t)zi0 * D_ + d0;
#pragma unroll 4
  for (int r2 = 0; r2 < 32; ++r2) {
    ushort4 u = vp[r2 * (D_ / 4)];
    f32x4 vi;
    vi[0] = __half2float(__ushort_as_half(u.x));
    vi[1] = __half2float(__ushort_as_half(u.y));
    vi[2] = __half2float(__ushort_as_half(u.z));
    vi[3] = __half2float(__ushort_as_half(u.w));
    float iv = sInv[r2], cd = sCd[r2];
    f32x4 o;
    o[0] = run[0] * iv + cd * vi[0];
    o[1] = run[1] * iv + cd * vi[1];
    o[2] = run[2] * iv + cd * vi[2];
    o[3] = run[3] * iv + cd * vi[3];
    *(f32x4*)(op + (size_t)r2 * D_) = o;
    run[0] += vi[0]; run[1] += vi[1]; run[2] += vi[2]; run[3] += vi[3];
  }
}

extern "C" void kernel_launch(void* const* d_in, const int* in_sizes, int n_in,
                              void* d_out, int out_size, void* d_ws, size_t ws_size,
                              hipStream_t stream) {
  const float* x  = (const float*)d_in[0];
  const float* wq = (const float*)d_in[1];
  const float* bq = (const float*)d_in[2];
  const float* wk = (const float*)d_in[3];
  const float* bk = (const float*)d_in[4];
  const float* wv = (const float*)d_in[5];
  const float* bv = (const float*)d_in[6];
  float* out = (float*)d_out;
  char* ws = (char*)d_ws;

  __half* wcat = (__half*)(ws + OFF_WCAT);
  float*  bcat = (float*)(ws + OFF_BCAT);
  __half* xb   = (__half*)(ws + OFF_XB);
  __half* q    = (__half*)(ws + OFF_Q);
  __half* k    = (__half*)(ws + OFF_K);
  __half* v    = (__half*)(ws + OFF_V);
  float* Zpart = (float*)(ws + OFF_ZP);
  float* dexp  = (float*)(ws + OFF_DEXP);
  float* Sv    = (float*)(ws + OFF_SV);

  k_prep<<<dim3(2048), dim3(256), 0, stream>>>(x, wq, wk, wv, bq, bk, bv, xb, wcat, bcat);
  k_qkv<<<dim3(64 * 24), dim3(256), 0, stream>>>(xb, wcat, bcat, q, k, v);
  k_statsv<<<dim3(672), dim3(256), 0, stream>>>(q, k, v, Zpart, dexp, Sv);
  k_out<<<dim3(256), dim3(256), 0, stream>>>(v, Sv, Zpart, dexp, out);
}

// Round 17
// 127.597 us; speedup vs baseline: 1.1417x; 1.0015x over previous
//
#include <hip/hip_runtime.h>
#include <hip/hip_fp16.h>
#include <cstdint>

typedef _Float16 half8_t __attribute__((ext_vector_type(8)));
typedef float f32x4 __attribute__((ext_vector_type(4)));

#define D_ 1024
#define B_ 4
#define N_ 2048
#define M_ (B_*N_)   // 8192 rows
#define NC_ 3072     // fused q|k|v output cols

// ---------------- workspace layout (bytes, all 256-aligned) ----------------
#define OFF_WCAT  0u            // 3072*1024*2  = 6291456
#define OFF_BCAT  6291456u      // 3072*4       = 12288
#define OFF_XB    6303744u      // 8192*1024*2  = 16777216
#define OFF_Q     23080960u
#define OFF_K     39858176u
#define OFF_V     56635392u
#define OFF_ZP    73412608u     // 8192*32*4    = 1048576
#define OFF_DEXP  74461184u     // 8192*4
#define OFF_SV    74493952u     // 4*64*1024*4 = 1048576 (32-row chunk sums, f32)

// ---------------- async global->LDS, 16B per lane ----------------
__device__ __forceinline__ void gload_lds16(const void* g, void* l) {
  __builtin_amdgcn_global_load_lds(
      (const __attribute__((address_space(1))) unsigned int*)(uintptr_t)g,
      (__attribute__((address_space(3))) unsigned int*)(uintptr_t)l, 16, 0, 0);
}

// ============================================================================
// 128^2 m97-structure core (proven 59.2us for qkv; fine-granularity packing)
// ============================================================================
__device__ __forceinline__ void stage128x64(const __half* rowbase, char* lds, int tid) {
#pragma unroll
  for (int inst = 0; inst < 4; ++inst) {
    int L  = inst * 4096 + tid * 16;
    int r  = L >> 7;
    int cb = L & 127;
    int cbs = cb ^ ((r & 7) << 4);
    gload_lds16((const char*)rowbase + (size_t)r * (D_ * 2) + cbs, lds + L);
  }
}

__device__ __forceinline__ half8_t ldsfrag(const char* lds, int row, int cbyte) {
  int b = (row << 7) + (cbyte ^ ((row & 7) << 4));
  return *reinterpret_cast<const half8_t*>(lds + b);
}

__device__ __forceinline__ void gemm128_core(const __half* Arow0, const __half* Brow0,
                                             char* As, char* Bs, f32x4 acc[4][4]) {
  const int tid  = threadIdx.x;
  const int lane = tid & 63;
  const int wave = tid >> 6;
  const int wm = wave >> 1, wn = wave & 1;
  for (int kt = 0; kt < 16; ++kt) {
    if (kt) __syncthreads();
    stage128x64(Arow0 + kt * 64, As, tid);
    stage128x64(Brow0 + kt * 64, Bs, tid);
    asm volatile("s_waitcnt vmcnt(0)" ::: "memory");
    __syncthreads();
#pragma unroll
    for (int kk = 0; kk < 2; ++kk) {
      const int cbyte = kk * 64 + (lane >> 4) * 16;
      half8_t a[4], b[4];
#pragma unroll
      for (int mf = 0; mf < 4; ++mf) a[mf] = ldsfrag(As, wm * 64 + mf * 16 + (lane & 15), cbyte);
#pragma unroll
      for (int nf = 0; nf < 4; ++nf) b[nf] = ldsfrag(Bs, wn * 64 + nf * 16 + (lane & 15), cbyte);
#pragma unroll
      for (int mf = 0; mf < 4; ++mf)
#pragma unroll
        for (int nf = 0; nf < 4; ++nf)
          acc[mf][nf] = __builtin_amdgcn_mfma_f32_16x16x32_f16(a[mf], b[nf], acc[mf][nf], 0, 0, 0);
    }
  }
}

// ---------------- K1: fp32->fp16 convert ----------------
__global__ __launch_bounds__(256) void k_prep(
    const float* __restrict__ x, const float* __restrict__ wq, const float* __restrict__ wk,
    const float* __restrict__ wv, const float* __restrict__ bq, const float* __restrict__ bk,
    const float* __restrict__ bv, __half* __restrict__ xb, __half* __restrict__ wcat,
    float* __restrict__ bcat) {
  const int NX4 = (M_ * D_) / 4;
  const int NW4 = (D_ * D_) / 4;
  const int TOT = NX4 + 3 * NW4;
  int tid0 = blockIdx.x * 256 + threadIdx.x;
  int stride = gridDim.x * 256;
  for (int i = tid0; i < TOT; i += stride) {
    float4 f; __half* dst;
    if (i < NX4) {
      f = ((const float4*)x)[i];
      dst = xb + 4 * (size_t)i;
    } else {
      int j = i - NX4; int w = j / NW4; int o = j - w * NW4;
      const float* src = (w == 0) ? wq : (w == 1) ? wk : wv;
      f = ((const float4*)src)[o];
      dst = wcat + (size_t)w * (D_ * D_) + 4 * (size_t)o;
    }
    __half h0 = __float2half(f.x), h1 = __float2half(f.y),
           h2 = __float2half(f.z), h3 = __float2half(f.w);
    ushort4 u = { __half_as_ushort(h0), __half_as_ushort(h1),
                  __half_as_ushort(h2), __half_as_ushort(h3) };
    *((ushort4*)dst) = u;
  }
  if (tid0 < NC_)
    bcat[tid0] = (tid0 < 1024) ? bq[tid0] : (tid0 < 2048) ? bk[tid0 - 1024] : bv[tid0 - 2048];
}

// ---------------- K2: fused QKV GEMM (128^2) + XCD bm-chunked swizzle ------
__global__ __launch_bounds__(256) void k_qkv(
    const __half* __restrict__ xb, const __half* __restrict__ wcat,
    const float* __restrict__ bcat,
    __half* __restrict__ q, __half* __restrict__ kx, __half* __restrict__ v) {
  __shared__ __align__(16) char smem[32768];
  char* As = smem; char* Bs = smem + 16384;
  int bid = blockIdx.x;
  int wgid = (bid & 7) * 192 + (bid >> 3);   // bijective: 1536 = 8*192
  int bm = wgid / 24, bn = wgid % 24;
  f32x4 acc[4][4];
#pragma unroll
  for (int i = 0; i < 4; ++i)
#pragma unroll
    for (int j = 0; j < 4; ++j) acc[i][j] = f32x4{0.f, 0.f, 0.f, 0.f};
  gemm128_core(xb + (size_t)bm * 128 * D_, wcat + (size_t)bn * 128 * D_, As, Bs, acc);

  const int lane = threadIdx.x & 63;
  const int wave = threadIdx.x >> 6;
  const int wm = wave >> 1, wn = wave & 1;
  int sel = bn >> 3;
  __half* outp = (sel == 0) ? q : (sel == 1) ? kx : v;
#pragma unroll
  for (int nf = 0; nf < 4; ++nf) {
    int nloc = wn * 64 + nf * 16 + (lane & 15);
    float bias = bcat[bn * 128 + nloc];
    int ncol = (bn & 7) * 128 + nloc;
#pragma unroll
    for (int mf = 0; mf < 4; ++mf) {
#pragma unroll
      for (int r = 0; r < 4; ++r) {
        int m = bm * 128 + wm * 64 + mf * 16 + (lane >> 4) * 4 + r;
        outp[(size_t)m * D_ + ncol] = __float2half(acc[mf][nf][r] + bias);
      }
    }
  }
}

// ============================================================================
// K3: 544 stats tiles (128^2, fine granularity) + 128 Sv blocks x 2 slabs.
// Grid 672 = 8*84, XCD-chunked. Stats tiles co-resident 2-3/CU -> good pack.
// ============================================================================
__global__ __launch_bounds__(256) void k_statsv(
    const __half* __restrict__ q, const __half* __restrict__ kx,
    const __half* __restrict__ v,
    float* __restrict__ Zpart, float* __restrict__ dexp, float* __restrict__ Sv) {
  __shared__ __align__(16) char smem[32768];
  int bid = blockIdx.x;
  int tile = (bid & 7) * 84 + (bid >> 3);       // 672 = 8*84

  if (tile >= 544) {
    // ---- Sv path: 2 slabs of 32-row chunk column sums per block ----
    int sid = tile - 544;                 // 0..127
    int dg = threadIdx.x;
    int d0 = dg * 4;
#pragma unroll
    for (int it = 0; it < 2; ++it) {
      int slab = sid * 2 + it;            // 0..255
      int b = slab >> 6, c = slab & 63;
      const ushort4* vp = (const ushort4*)(v + ((size_t)(b * N_ + c * 32)) * D_ + d0);
      f32x4 s = {0.f, 0.f, 0.f, 0.f};
#pragma unroll 8
      for (int r2 = 0; r2 < 32; ++r2) {
        ushort4 u = vp[r2 * (D_ / 4)];
        s[0] += __half2float(__ushort_as_half(u.x));
        s[1] += __half2float(__ushort_as_half(u.y));
        s[2] += __half2float(__ushort_as_half(u.z));
        s[3] += __half2float(__ushort_as_half(u.w));
      }
      *(f32x4*)(Sv + (size_t)slab * D_ + d0) = s;
    }
    return;
  }

  // ---- stats tile (r1-proven 128^2 math) ----
  int b = tile / 136;
  int r = tile % 136;
  int ti = 0;
  while (r >= 16 - ti) { r -= 16 - ti; ++ti; }
  int tj = ti + r;

  f32x4 acc[4][4];
#pragma unroll
  for (int i = 0; i < 4; ++i)
#pragma unroll
    for (int j = 0; j < 4; ++j) acc[i][j] = f32x4{0.f, 0.f, 0.f, 0.f};
  const size_t base = (size_t)b * N_ * D_;
  gemm128_core(q + base + (size_t)ti * 128 * D_, kx + base + (size_t)tj * 128 * D_,
               smem, smem + 16384, acc);

  const int lane = threadIdx.x & 63;
  const int wave = threadIdx.x >> 6;
  const int wm = wave >> 1, wn = wave & 1;
  const bool offd = (tj > ti);
  const float scale = 0.03125f;            // 1/sqrt(1024)
  int zrow0 = b * N_ + ti * 128;
#pragma unroll
  for (int mf = 0; mf < 4; ++mf) {
#pragma unroll
    for (int rg = 0; rg < 4; ++rg) {
      int il = wm * 64 + mf * 16 + (lane >> 4) * 4 + rg;
      float ssum = 0.f;
#pragma unroll
      for (int nf = 0; nf < 4; ++nf) {
        int jl = wn * 64 + nf * 16 + (lane & 15);
        float e = __expf(acc[mf][nf][rg] * scale);
        bool keep = offd || (jl >= il);
        if (!offd && jl == il) dexp[zrow0 + il] = e;
        ssum += keep ? e : 0.f;
      }
      ssum += __shfl_xor(ssum, 1);
      ssum += __shfl_xor(ssum, 2);
      ssum += __shfl_xor(ssum, 4);
      ssum += __shfl_xor(ssum, 8);
      if ((lane & 15) == 0)
        Zpart[(size_t)(zrow0 + il) * 32 + tj * 2 + wn] = ssum;
    }
  }
}

// ---------------- K4: denom + prefix-scan blend -> output (vec4) ----------
__global__ __launch_bounds__(256) void k_out(
    const __half* __restrict__ v, const float* __restrict__ Sv,
    const float* __restrict__ Zpart, const float* __restrict__ dexp,
    float* __restrict__ out) {
  __shared__ float sInv[32], sCd[32];
  int slab = blockIdx.x;
  int b = slab >> 6, c = slab & 63;
  int dg = threadIdx.x;
  int d0 = dg * 4;
  int zi0 = b * N_ + c * 32;

  if (dg < 32) {
    int i  = c * 32 + dg;                 // row within batch
    int row = zi0 + dg;
    int t0 = (i >> 7) * 2;                // first valid Zpart slot (128-tiles)
    float z = 0.f;
    for (int t = t0; t < 32; ++t) z += Zpart[(size_t)row * 32 + t];
    float iv = 1.f / ((float)i + z);
    sInv[dg] = iv;
    sCd[dg]  = dexp[row] * iv;
  }
  __syncthreads();

  f32x4 run = {0.f, 0.f, 0.f, 0.f};
  for (int cc = 0; cc < c; ++cc) {
    f32x4 sv = *(const f32x4*)(Sv + (size_t)((b << 6) + cc) * D_ + d0);
    run[0] += sv[0]; run[1] += sv[1]; run[2] += sv[2]; run[3] += sv[3];
  }
  const ushort4* vp = (const ushort4*)(v + (size_t)zi0 * D_ + d0);
  float* op = out + (size_t)zi0 * D_ + d0;
#pragma unroll 4
  for (int r2 = 0; r2 < 32; ++r2) {
    ushort4 u = vp[r2 * (D_ / 4)];
    f32x4 vi;
    vi[0] = __half2float(__ushort_as_half(u.x));
    vi[1] = __half2float(__ushort_as_half(u.y));
    vi[2] = __half2float(__ushort_as_half(u.z));
    vi[3] = __half2float(__ushort_as_half(u.w));
    float iv = sInv[r2], cd = sCd[r2];
    f32x4 o;
    o[0] = run[0] * iv + cd * vi[0];
    o[1] = run[1] * iv + cd * vi[1];
    o[2] = run[2] * iv + cd * vi[2];
    o[3] = run[3] * iv + cd * vi[3];
    *(f32x4*)(op + (size_t)r2 * D_) = o;
    run[0] += vi[0]; run[1] += vi[1]; run[2] += vi[2]; run[3] += vi[3];
  }
}

extern "C" void kernel_launch(void* const* d_in, const int* in_sizes, int n_in,
                              void* d_out, int out_size, void* d_ws, size_t ws_size,
                              hipStream_t stream) {
  const float* x  = (const float*)d_in[0];
  const float* wq = (const float*)d_in[1];
  const float* bq = (const float*)d_in[2];
  const float* wk = (const float*)d_in[3];
  const float* bk = (const float*)d_in[4];
  const float* wv = (const float*)d_in[5];
  const float* bv = (const float*)d_in[6];
  float* out = (float*)d_out;
  char* ws = (char*)d_ws;

  __half* wcat = (__half*)(ws + OFF_WCAT);
  float*  bcat = (float*)(ws + OFF_BCAT);
  __half* xb   = (__half*)(ws + OFF_XB);
  __half* q    = (__half*)(ws + OFF_Q);
  __half* k    = (__half*)(ws + OFF_K);
  __half* v    = (__half*)(ws + OFF_V);
  float* Zpart = (float*)(ws + OFF_ZP);
  float* dexp  = (float*)(ws + OFF_DEXP);
  float* Sv    = (float*)(ws + OFF_SV);

  k_prep<<<dim3(2048), dim3(256), 0, stream>>>(x, wq, wk, wv, bq, bk, bv, xb, wcat, bcat);
  k_qkv<<<dim3(64 * 24), dim3(256), 0, stream>>>(xb, wcat, bcat, q, k, v);
  k_statsv<<<dim3(672), dim3(256), 0, stream>>>(q, k, v, Zpart, dexp, Sv);
  k_out<<<dim3(256), dim3(256), 0, stream>>>(v, Sv, Zpart, dexp, out);
}